// Round 3
// baseline (362.739 us; speedup 1.0000x reference)
//
#include <hip/hip_runtime.h>
#include <hip/hip_bf16.h>

// Problem constants
#define BATCH 16384
#define F1    1024
#define F2    512
#define NCLS  64
#define NEXP  8
#define SEG   128                 // expert segment granularity (= gemm1 BM)
#define BPAD  (BATCH + NEXP*SEG)  // 17408
#define NB1   (BPAD / 128)        // 136 gemm1 m-blocks
#define NB2   (BPAD / 32)         // 544 gemm2 m-blocks

typedef __attribute__((ext_vector_type(8))) short short8;   // 8 bf16
typedef __attribute__((ext_vector_type(4))) float float4v;  // MFMA C/D

// Workspace layout (bytes)
#define O_META   0                        // cursors[8]@8, bases[8]@16
#define O_BEXP   128                      // int[136]
#define O_ORDER  704                      // int[17408]
#define O_ZROW   70336                    // bf16[1024] zeros (pad-row source)
#define O_XHI    72448                    // bf16[16384][1024]
#define O_XLO    (O_XHI + 33554432)
#define O_W1HI   (O_XLO + 33554432)       // bf16[8][512][1024]  [e][n][k]
#define O_W1LO   (O_W1HI + 8388608)
#define O_W2HI   (O_W1LO + 8388608)       // bf16[8][64][512]    [e][c][f2]
#define O_W2LO   (O_W2HI + 524288)
#define O_HHI    (O_W2LO + 524288)        // bf16[17408][512]
#define O_HLO    (O_HHI + 17825792)

__device__ inline short bf16_rn(float f) {
    unsigned u = __builtin_bit_cast(unsigned, f);
    u = (u + 0x7fffu + ((u >> 16) & 1u)) >> 16;
    return (short)u;
}
__device__ inline float bf16_up(short h) {
    return __builtin_bit_cast(float, ((unsigned)(unsigned short)h) << 16);
}
__device__ inline void split2(float v, short& hi, short& lo) {
    hi = bf16_rn(v);
    lo = bf16_rn(v - bf16_up(hi));
}
__device__ inline float4v mfma16(short8 a, short8 b, float4v c) {
    return __builtin_amdgcn_mfma_f32_16x16x32_bf16(a, b, c, 0, 0, 0);
}
__device__ inline void glds16(const void* g, void* l) {
    __builtin_amdgcn_global_load_lds((const __attribute__((address_space(1))) void*)g,
                                     (__attribute__((address_space(3))) void*)l,
                                     16, 0, 0);
}

// ---------------- setup: order-init + zrow + histogram + plan + bexp (1 block) ----------------
__global__ __launch_bounds__(1024)
void dael_setup(const int* __restrict__ domain, int* meta, int* bexp, int* order, int* zrow) {
    const int tid = threadIdx.x;
    for (int i = tid; i < BPAD; i += 1024) order[i] = -1;
    if (tid < 512) zrow[tid] = 0;
    int c[NEXP];
    #pragma unroll
    for (int e = 0; e < NEXP; ++e) c[e] = 0;
    for (int i = tid; i < BATCH; i += 1024) {
        int d = domain[i];
        #pragma unroll
        for (int e = 0; e < NEXP; ++e) c[e] += (d == e);
    }
    __shared__ int sc[NEXP];
    __shared__ int soff[NEXP + 1];
    if (tid < NEXP) sc[tid] = 0;
    __syncthreads();
    #pragma unroll
    for (int e = 0; e < NEXP; ++e) {
        int v = c[e];
        #pragma unroll
        for (int off = 32; off > 0; off >>= 1) v += __shfl_down(v, off, 64);
        if ((tid & 63) == 0 && v) atomicAdd(&sc[e], v);
    }
    __syncthreads();
    if (tid == 0) {
        int acc = 0;
        for (int e = 0; e < NEXP; ++e) {
            soff[e] = acc;
            meta[16 + e] = acc * 128;   // padded row base
            meta[8 + e]  = 0;           // cursor
            acc += (sc[e] + 127) >> 7;
        }
        soff[NEXP] = acc;
    }
    __syncthreads();
    for (int i = tid; i < NB1; i += 1024) {
        int ee = -1;
        #pragma unroll
        for (int e = 0; e < NEXP; ++e)
            if (i >= soff[e] && i < soff[e + 1]) ee = e;
        bexp[i] = ee;
    }
}

// per-block LDS ranks: 8 global atomics per block
__global__ void dael_scatter(const int* __restrict__ domain, int* meta, int* order) {
    __shared__ int lc[NEXP], lb[NEXP];
    const int tid = threadIdx.x;
    const int i = blockIdx.x * 256 + tid;
    if (tid < NEXP) lc[tid] = 0;
    __syncthreads();
    const int d = domain[i];
    const int r = atomicAdd(&lc[d], 1);
    __syncthreads();
    if (tid < NEXP && lc[tid] > 0) lb[tid] = atomicAdd(&meta[8 + tid], lc[tid]);
    __syncthreads();
    order[meta[16 + d] + lb[d] + r] = i;
}

// ---------------- convert mega-kernel: xsplit | convw1 | convw2 ----------------
#define NBX 8192
#define NBW1 4096
#define NBW2 256
__global__ __launch_bounds__(256)
void dael_convert(const float* __restrict__ x, short* xhi, short* xlo,
                  const float* __restrict__ W1, short* w1hi, short* w1lo,
                  const float* __restrict__ W2, short* w2hi, short* w2lo) {
    __shared__ float tile[32][33];
    const int b = blockIdx.x;
    if (b < NBX) {
        const size_t i8 = (size_t)(b * 256 + threadIdx.x) * 8;
        float4 f0 = *(const float4*)(x + i8);
        float4 f1 = *(const float4*)(x + i8 + 4);
        float va[8] = {f0.x, f0.y, f0.z, f0.w, f1.x, f1.y, f1.z, f1.w};
        short8 vh, vl;
        #pragma unroll
        for (int q = 0; q < 8; ++q) { short h, l; split2(va[q], h, l); vh[q] = h; vl[q] = l; }
        *(short8*)(xhi + i8) = vh;
        *(short8*)(xlo + i8) = vl;
    } else if (b < NBX + NBW1) {
        const int b2 = b - NBX;
        const int e = b2 >> 9, rem = b2 & 511;
        const int k0 = (rem >> 4) << 5, n0 = (rem & 15) << 5;
        const int c = threadIdx.x & 31, r0 = threadIdx.x >> 5;
        #pragma unroll
        for (int i = 0; i < 4; ++i) {
            int r = r0 + i * 8;
            tile[r][c] = W1[((size_t)(e * F1 + k0 + r)) * F2 + n0 + c];
        }
        __syncthreads();
        #pragma unroll
        for (int i = 0; i < 4; ++i) {
            int r = r0 + i * 8;
            float v = tile[c][r];
            size_t off = ((size_t)(e * F2 + n0 + r)) * F1 + k0 + c;
            short hi, lo; split2(v, hi, lo);
            w1hi[off] = hi; w1lo[off] = lo;
        }
    } else {
        const int b3 = b - NBX - NBW1;
        const int e = b3 >> 5, rem = b3 & 31;
        const int k0 = (rem >> 1) << 5, n0 = (rem & 1) << 5;
        const int c = threadIdx.x & 31, r0 = threadIdx.x >> 5;
        #pragma unroll
        for (int i = 0; i < 4; ++i) {
            int r = r0 + i * 8;
            tile[r][c] = W2[((size_t)(e * F2 + k0 + r)) * NCLS + n0 + c];
        }
        __syncthreads();
        #pragma unroll
        for (int i = 0; i < 4; ++i) {
            int r = r0 + i * 8;
            float v = tile[c][r];
            size_t off = ((size_t)(e * NCLS + n0 + r)) * F2 + k0 + c;
            short hi, lo; split2(v, hi, lo);
            w2hi[off] = hi; w2lo[off] = lo;
        }
    }
}

// ---------------- GEMM1: 128x128 tile, 512 thr / 8 waves, in-block split-K ----------------
// Waves 0-3: 64x64 regions, k in [0,32) of each BK=64 slab; waves 4-7: k in [32,64).
// LDS chunk-major [chunk][row][16B] -> bank floor; fp32 cross-wave reduce at end.
__global__ __launch_bounds__(512, 4)
void dael_gemm1(const int* __restrict__ order, const int* __restrict__ bexp,
                const short* __restrict__ xhi, const short* __restrict__ xlo,
                const short* __restrict__ zrow,
                const short* __restrict__ w1hi, const short* __restrict__ w1lo,
                const float* __restrict__ b1,
                short* __restrict__ hhi, short* __restrict__ hlo) {
    const int e = bexp[blockIdx.x];
    if (e < 0) return;
    const int p0 = blockIdx.x * 128;
    const int n0 = blockIdx.y * 128;
    const int tid = threadIdx.x;
    const int lane = tid & 63, wv = tid >> 6;
    const int quad = lane >> 4, lrow = lane & 15;
    const int khalf = wv >> 2;
    const int r0w = (wv & 1) * 64, c0w = ((wv >> 1) & 1) * 64;

    __shared__ __align__(16) char SMc[65536];  // 4 planes x [8][128][16B]=16KB

    // staging: slot s = tid + 512j -> chunk s>>7, row s&127 (same row both j)
    const int arow = tid & 127;
    const int cel0 = (tid >> 7) * 8;        // element offset of chunk j=0; j=1 adds 32
    const int samp = order[p0 + arow];
    const short* pxh = (samp >= 0 ? xhi + (size_t)samp * F1 : zrow);
    const short* pxl = (samp >= 0 ? xlo + (size_t)samp * F1 : zrow);
    const short* pbh = w1hi + (size_t)(e * F2 + n0 + arow) * F1;
    const short* pbl = w1lo + (size_t)(e * F2 + n0 + arow) * F1;
    const int d0 = tid * 16, d1 = d0 + 8192;

    float4v acc[4][4] = {};
    int offa[4], offb[4];
    #pragma unroll
    for (int i = 0; i < 4; ++i)
        offa[i] = ((khalf * 4 + quad) * 128 + r0w + i * 16 + lrow) * 16;
    #pragma unroll
    for (int j = 0; j < 4; ++j)
        offb[j] = ((khalf * 4 + quad) * 128 + c0w + j * 16 + lrow) * 16;

    for (int k0 = 0; k0 < F1; k0 += 64) {
        __syncthreads();
        glds16(pxh + k0 + cel0,      SMc + d0);           // A hi
        glds16(pxh + k0 + cel0 + 32, SMc + d1);
        glds16(pxl + k0 + cel0,      SMc + 16384 + d0);   // A lo
        glds16(pxl + k0 + cel0 + 32, SMc + 16384 + d1);
        glds16(pbh + k0 + cel0,      SMc + 32768 + d0);   // B hi
        glds16(pbh + k0 + cel0 + 32, SMc + 32768 + d1);
        glds16(pbl + k0 + cel0,      SMc + 49152 + d0);   // B lo
        glds16(pbl + k0 + cel0 + 32, SMc + 49152 + d1);
        __syncthreads();
        short8 ah[4], al[4];
        #pragma unroll
        for (int i = 0; i < 4; ++i) {
            ah[i] = *(const short8*)(SMc + offa[i]);
            al[i] = *(const short8*)(SMc + 16384 + offa[i]);
        }
        #pragma unroll
        for (int j = 0; j < 4; ++j) {
            short8 bh = *(const short8*)(SMc + 32768 + offb[j]);
            short8 bl = *(const short8*)(SMc + 49152 + offb[j]);
            #pragma unroll
            for (int i = 0; i < 4; ++i) {
                acc[i][j] = mfma16(ah[i], bh, acc[i][j]);
                acc[i][j] = mfma16(ah[i], bl, acc[i][j]);
                acc[i][j] = mfma16(al[i], bh, acc[i][j]);
            }
        }
    }

    // cross k-half reduction through LDS (swizzled cols: 2-way max)
    __syncthreads();
    float* red = (float*)SMc;
    if (khalf) {
        float* dst = red + (wv & 3) * 4096;
        #pragma unroll
        for (int i = 0; i < 4; ++i)
            #pragma unroll
            for (int j = 0; j < 4; ++j)
                #pragma unroll
                for (int r = 0; r < 4; ++r) {
                    const int m = i * 16 + quad * 4 + r;
                    const int n = j * 16 + lrow;
                    dst[m * 64 + ((n + 4 * m) & 63)] = acc[i][j][r];
                }
    }
    __syncthreads();
    float bv[4];
    #pragma unroll
    for (int j = 0; j < 4; ++j) bv[j] = b1[e * F2 + n0 + c0w + j * 16 + lrow];
    if (!khalf) {
        const float* src = red + wv * 4096;
        #pragma unroll
        for (int i = 0; i < 4; ++i)
            #pragma unroll
            for (int j = 0; j < 4; ++j)
                #pragma unroll
                for (int r = 0; r < 4; ++r) {
                    const int m = i * 16 + quad * 4 + r;
                    const int n = j * 16 + lrow;
                    acc[i][j][r] += src[m * 64 + ((n + 4 * m) & 63)];
                }
    }

    // epilogue: +b1, relu, split; two row-halves through LDS [2][64][132]
    short* T = (short*)SMc;
    #pragma unroll
    for (int rh = 0; rh < 2; ++rh) {
        __syncthreads();
        if (!khalf && (wv & 1) == rh) {
            #pragma unroll
            for (int i = 0; i < 4; ++i)
                #pragma unroll
                for (int j = 0; j < 4; ++j)
                    #pragma unroll
                    for (int r = 0; r < 4; ++r) {
                        const int m = i * 16 + quad * 4 + r;
                        const int n = c0w + j * 16 + lrow;
                        float hv = fmaxf(acc[i][j][r] + bv[j], 0.f);
                        short hi = bf16_rn(hv);
                        T[m * 132 + n] = hi;
                        T[8448 + m * 132 + n] = bf16_rn(hv - bf16_up(hi));
                    }
        }
        __syncthreads();
        const int row = tid >> 3, cb = tid & 7;
        const size_t gb = (size_t)(p0 + rh * 64 + row) * F2 + n0;
        #pragma unroll
        for (int u = 0; u < 4; ++u) {
            const int cc = (cb + u * 8) * 4;   // 4-short chunks
            *(uint2*)(hhi + gb + cc) = *(const uint2*)&T[row * 132 + cc];
            *(uint2*)(hlo + gb + cc) = *(const uint2*)&T[8448 + row * 132 + cc];
        }
    }
}

// ---------------- GEMM2: 32 rows x 64 classes, BK=64, chunk-major staging; softmax ----------------
__global__ __launch_bounds__(256)
void dael_gemm2(const int* __restrict__ order, const int* __restrict__ bexp,
                const short* __restrict__ hhi, const short* __restrict__ hlo,
                const short* __restrict__ w2hi, const short* __restrict__ w2lo,
                const float* __restrict__ b2, float* __restrict__ out) {
    const int e = bexp[blockIdx.x >> 2];
    if (e < 0) return;
    const int p0 = blockIdx.x * 32;
    const int tid = threadIdx.x;
    const int lane = tid & 63, wv = tid >> 6;
    const int quad = lane >> 4, lrow = lane & 15;

    __shared__ __align__(16) char SM2[24576]; // Ahi[8][32][16] Alo | Bhi[8][64][16] Blo
    __shared__ float L[32][68];
    __shared__ float inv[32];

    const int arow = tid & 31;
    const int acel = (tid >> 5) * 8;
    const int brow = tid & 63;
    const int bcel = (tid >> 6) * 8;
    const size_t abase = (size_t)(p0 + arow) * F2 + acel;
    const size_t bbase = (size_t)(e * NCLS + brow) * F2 + bcel;
    const int da = tid * 16;
    const int db1 = da + 4096;

    float4v acc[2] = {};

    for (int k0 = 0; k0 < F2; k0 += 64) {
        __syncthreads();
        glds16(hhi + abase + k0,       SM2 + da);             // A hi
        glds16(hlo + abase + k0,       SM2 + 4096 + da);      // A lo
        glds16(w2hi + bbase + k0,      SM2 + 8192 + da);      // B hi c0-3
        glds16(w2hi + bbase + k0 + 32, SM2 + 8192 + db1);     // B hi c4-7
        glds16(w2lo + bbase + k0,      SM2 + 16384 + da);     // B lo
        glds16(w2lo + bbase + k0 + 32, SM2 + 16384 + db1);
        __syncthreads();
        #pragma unroll
        for (int s = 0; s < 2; ++s) {
            const int ch = s * 4 + quad;
            const int bo = (ch * 64 + wv * 16 + lrow) * 16;
            short8 bh = *(const short8*)(SM2 + 8192 + bo);
            short8 bl = *(const short8*)(SM2 + 16384 + bo);
            #pragma unroll
            for (int i = 0; i < 2; ++i) {
                const int ao = (ch * 32 + i * 16 + lrow) * 16;
                short8 ahf = *(const short8*)(SM2 + ao);
                short8 alf = *(const short8*)(SM2 + 4096 + ao);
                acc[i] = mfma16(ahf, bh, acc[i]);
                acc[i] = mfma16(ahf, bl, acc[i]);
                acc[i] = mfma16(alf, bh, acc[i]);
            }
        }
    }

    const int n = wv * 16 + lrow;
    const float bb = b2[e * NCLS + n];
    #pragma unroll
    for (int i = 0; i < 2; ++i)
        #pragma unroll
        for (int r = 0; r < 4; ++r)
            L[i * 16 + quad * 4 + r][n] = acc[i][r] + bb;
    __syncthreads();
    if (tid < 32) {
        float mx = -3.402823466e38f;
        #pragma unroll 8
        for (int c = 0; c < NCLS; ++c) mx = fmaxf(mx, L[tid][c]);
        float s = 0.f;
        #pragma unroll 8
        for (int c = 0; c < NCLS; ++c) { float ev = __expf(L[tid][c] - mx); L[tid][c] = ev; s += ev; }
        inv[tid] = 1.f / s;
    }
    __syncthreads();
    if (tid < 128) {
        const int r = tid >> 2, cs = (tid & 3) * 16;
        const int samp = order[p0 + r];
        if (samp >= 0) {
            const float sc = inv[r];
            #pragma unroll
            for (int q = 0; q < 4; ++q) {
                float4 v = *(const float4*)&L[r][cs + q * 4];
                v.x *= sc; v.y *= sc; v.z *= sc; v.w *= sc;
                *(float4*)(out + (size_t)samp * NCLS + cs + q * 4) = v;
            }
        }
    }
}

extern "C" void kernel_launch(void* const* d_in, const int* in_sizes, int n_in,
                              void* d_out, int out_size, void* d_ws, size_t ws_size,
                              hipStream_t stream) {
    const int*   domain = (const int*)d_in[0];
    const float* x      = (const float*)d_in[1];
    const float* W1     = (const float*)d_in[2];
    const float* b1     = (const float*)d_in[3];
    const float* W2     = (const float*)d_in[4];
    const float* b2     = (const float*)d_in[5];
    float* out = (float*)d_out;

    char* ws = (char*)d_ws;
    int*   meta  = (int*)(ws + O_META);
    int*   bexp  = (int*)(ws + O_BEXP);
    int*   order = (int*)(ws + O_ORDER);
    short* zrow  = (short*)(ws + O_ZROW);
    short* xhi   = (short*)(ws + O_XHI);
    short* xlo   = (short*)(ws + O_XLO);
    short* w1hi  = (short*)(ws + O_W1HI);
    short* w1lo  = (short*)(ws + O_W1LO);
    short* w2hi  = (short*)(ws + O_W2HI);
    short* w2lo  = (short*)(ws + O_W2LO);
    short* hhi   = (short*)(ws + O_HHI);
    short* hlo   = (short*)(ws + O_HLO);

    dael_setup<<<1, 1024, 0, stream>>>(domain, meta, bexp, order, (int*)zrow);
    dael_scatter<<<BATCH / 256, 256, 0, stream>>>(domain, meta, order);
    dael_convert<<<NBX + NBW1 + NBW2, 256, 0, stream>>>(x, xhi, xlo, W1, w1hi, w1lo,
                                                        W2, w2hi, w2lo);
    dael_gemm1<<<dim3(NB1, 4), 512, 0, stream>>>(order, bexp, xhi, xlo, zrow,
                                                 w1hi, w1lo, b1, hhi, hlo);
    dael_gemm2<<<NB2, 256, 0, stream>>>(order, bexp, hhi, hlo, w2hi, w2lo, b2, out);
}

// Round 4
// 309.546 us; speedup vs baseline: 1.1718x; 1.1718x over previous
//
#include <hip/hip_runtime.h>
#include <hip/hip_bf16.h>

// Problem constants
#define BATCH 16384
#define F1    1024
#define F2    512
#define NCLS  64
#define NEXP  8
#define SEG   64                  // expert segment granularity (= gemm1 BM)
#define BPAD  (BATCH + NEXP*SEG)  // 16896
#define NB1   (BPAD / 64)         // 264 gemm1 m-blocks
#define NB2   (BPAD / 32)         // 528 gemm2 m-blocks

typedef __attribute__((ext_vector_type(8))) short short8;   // 8 bf16
typedef __attribute__((ext_vector_type(4))) float float4v;  // MFMA C/D

// Workspace layout (bytes); total ~119.6 MB (<= round-2's proven 121 MB)
#define O_META   0                        // cursors[8]@8, bases[8]@16
#define O_BEXP   128                      // int[264]
#define O_ORDER  1280                     // int[16896]
#define O_ZROW   68864                    // bf16[1024] zeros (pad-row source)
#define O_XHI    70912                    // bf16[16384][1024]
#define O_XLO    (O_XHI + 33554432)
#define O_W1HI   (O_XLO + 33554432)       // bf16[8][512][1024]  [e][n][k]
#define O_W1LO   (O_W1HI + 8388608)
#define O_W2HI   (O_W1LO + 8388608)       // bf16[8][64][512]    [e][c][f2]
#define O_W2LO   (O_W2HI + 524288)
#define O_HHI    (O_W2LO + 524288)        // bf16[16896][512]
#define O_HLO    (O_HHI + 17301504)

__device__ inline short bf16_rn(float f) {
    unsigned u = __builtin_bit_cast(unsigned, f);
    u = (u + 0x7fffu + ((u >> 16) & 1u)) >> 16;
    return (short)u;
}
__device__ inline float bf16_up(short h) {
    return __builtin_bit_cast(float, ((unsigned)(unsigned short)h) << 16);
}
__device__ inline void split2(float v, short& hi, short& lo) {
    hi = bf16_rn(v);
    lo = bf16_rn(v - bf16_up(hi));
}
__device__ inline float4v mfma16(short8 a, short8 b, float4v c) {
    return __builtin_amdgcn_mfma_f32_16x16x32_bf16(a, b, c, 0, 0, 0);
}
__device__ inline void glds16(const void* g, void* l) {
    __builtin_amdgcn_global_load_lds((const __attribute__((address_space(1))) void*)g,
                                     (__attribute__((address_space(3))) void*)l,
                                     16, 0, 0);
}

// ---------------- setup: order-init + zrow + histogram + plan + bexp (1 block) ----------------
__global__ __launch_bounds__(1024)
void dael_setup(const int* __restrict__ domain, int* meta, int* bexp, int* order, int* zrow) {
    const int tid = threadIdx.x;
    for (int i = tid; i < BPAD; i += 1024) order[i] = -1;
    if (tid < 512) zrow[tid] = 0;
    int c[NEXP];
    #pragma unroll
    for (int e = 0; e < NEXP; ++e) c[e] = 0;
    for (int i = tid; i < BATCH; i += 1024) {
        int d = domain[i];
        #pragma unroll
        for (int e = 0; e < NEXP; ++e) c[e] += (d == e);
    }
    __shared__ int sc[NEXP];
    __shared__ int soff[NEXP + 1];
    if (tid < NEXP) sc[tid] = 0;
    __syncthreads();
    #pragma unroll
    for (int e = 0; e < NEXP; ++e) {
        int v = c[e];
        #pragma unroll
        for (int off = 32; off > 0; off >>= 1) v += __shfl_down(v, off, 64);
        if ((tid & 63) == 0 && v) atomicAdd(&sc[e], v);
    }
    __syncthreads();
    if (tid == 0) {
        int acc = 0;
        for (int e = 0; e < NEXP; ++e) {
            soff[e] = acc;
            meta[16 + e] = acc * 64;    // padded row base (SEG=64)
            meta[8 + e]  = 0;           // cursor
            acc += (sc[e] + 63) >> 6;
        }
        soff[NEXP] = acc;
    }
    __syncthreads();
    for (int i = tid; i < NB1; i += 1024) {
        int ee = -1;
        #pragma unroll
        for (int e = 0; e < NEXP; ++e)
            if (i >= soff[e] && i < soff[e + 1]) ee = e;
        bexp[i] = ee;
    }
}

// per-block LDS ranks: 8 global atomics per block
__global__ void dael_scatter(const int* __restrict__ domain, int* meta, int* order) {
    __shared__ int lc[NEXP], lb[NEXP];
    const int tid = threadIdx.x;
    const int i = blockIdx.x * 256 + tid;
    if (tid < NEXP) lc[tid] = 0;
    __syncthreads();
    const int d = domain[i];
    const int r = atomicAdd(&lc[d], 1);
    __syncthreads();
    if (tid < NEXP && lc[tid] > 0) lb[tid] = atomicAdd(&meta[8 + tid], lc[tid]);
    __syncthreads();
    order[meta[16 + d] + lb[d] + r] = i;
}

// ---------------- convert mega-kernel: xsplit | convw1 | convw2 ----------------
#define NBX 8192
#define NBW1 4096
#define NBW2 256
__global__ __launch_bounds__(256)
void dael_convert(const float* __restrict__ x, short* xhi, short* xlo,
                  const float* __restrict__ W1, short* w1hi, short* w1lo,
                  const float* __restrict__ W2, short* w2hi, short* w2lo) {
    __shared__ float tile[32][33];
    const int b = blockIdx.x;
    if (b < NBX) {
        const size_t i8 = (size_t)(b * 256 + threadIdx.x) * 8;
        float4 f0 = *(const float4*)(x + i8);
        float4 f1 = *(const float4*)(x + i8 + 4);
        float va[8] = {f0.x, f0.y, f0.z, f0.w, f1.x, f1.y, f1.z, f1.w};
        short8 vh, vl;
        #pragma unroll
        for (int q = 0; q < 8; ++q) { short h, l; split2(va[q], h, l); vh[q] = h; vl[q] = l; }
        *(short8*)(xhi + i8) = vh;
        *(short8*)(xlo + i8) = vl;
    } else if (b < NBX + NBW1) {
        const int b2 = b - NBX;
        const int e = b2 >> 9, rem = b2 & 511;
        const int k0 = (rem >> 4) << 5, n0 = (rem & 15) << 5;
        const int c = threadIdx.x & 31, r0 = threadIdx.x >> 5;
        #pragma unroll
        for (int i = 0; i < 4; ++i) {
            int r = r0 + i * 8;
            tile[r][c] = W1[((size_t)(e * F1 + k0 + r)) * F2 + n0 + c];
        }
        __syncthreads();
        #pragma unroll
        for (int i = 0; i < 4; ++i) {
            int r = r0 + i * 8;
            float v = tile[c][r];
            size_t off = ((size_t)(e * F2 + n0 + r)) * F1 + k0 + c;
            short hi, lo; split2(v, hi, lo);
            w1hi[off] = hi; w1lo[off] = lo;
        }
    } else {
        const int b3 = b - NBX - NBW1;
        const int e = b3 >> 5, rem = b3 & 31;
        const int k0 = (rem >> 1) << 5, n0 = (rem & 1) << 5;
        const int c = threadIdx.x & 31, r0 = threadIdx.x >> 5;
        #pragma unroll
        for (int i = 0; i < 4; ++i) {
            int r = r0 + i * 8;
            tile[r][c] = W2[((size_t)(e * F2 + k0 + r)) * NCLS + n0 + c];
        }
        __syncthreads();
        #pragma unroll
        for (int i = 0; i < 4; ++i) {
            int r = r0 + i * 8;
            float v = tile[c][r];
            size_t off = ((size_t)(e * NCLS + n0 + r)) * F2 + k0 + c;
            short hi, lo; split2(v, hi, lo);
            w2hi[off] = hi; w2lo[off] = lo;
        }
    }
}

// ---------------- GEMM1: BM=64 x BN=128, BK=32, 256 thr / 4 waves ----------------
// grid (264, 4). Chunk-major LDS [chunk][row][16B] (bank-clean, glds16-compatible).
// Wave w: rows (w&1)*32..+31, cols (w>>1)*64..+63 -> acc[2][4].
__global__ __launch_bounds__(256)
void dael_gemm1(const int* __restrict__ order, const int* __restrict__ bexp,
                const short* __restrict__ xhi, const short* __restrict__ xlo,
                const short* __restrict__ zrow,
                const short* __restrict__ w1hi, const short* __restrict__ w1lo,
                const float* __restrict__ b1,
                short* __restrict__ hhi, short* __restrict__ hlo) {
    const int e = bexp[blockIdx.x];
    if (e < 0) return;
    const int p0 = blockIdx.x * 64;
    const int n0 = blockIdx.y * 128;
    const int tid = threadIdx.x;
    const int lane = tid & 63, wv = tid >> 6;
    const int quad = lane >> 4, lrow = lane & 15;
    const int r0w = (wv & 1) * 32, c0w = (wv >> 1) * 64;

    // LDS: Ahi[4][64][16B]=4K @0, Alo @4096, Bhi[4][128][16B]=8K @8192, Blo @16384
    __shared__ __align__(16) char SMc[24576];

    // A staging: thread t -> chunk t>>6, row t&63; dst = t*16 (lane-contiguous)
    const int arow = tid & 63, achk = tid >> 6;
    const int samp = order[p0 + arow];
    const short* pxh = (samp >= 0 ? xhi + (size_t)samp * F1 : zrow) + achk * 8;
    const short* pxl = (samp >= 0 ? xlo + (size_t)samp * F1 : zrow) + achk * 8;
    // B staging: slots s = t (chunks 0-1) and t+256 (chunks 2-3); row s&127
    const int brow = tid & 127, bchk = tid >> 7;
    const short* pbh = w1hi + (size_t)(e * F2 + n0 + brow) * F1;
    const short* pbl = w1lo + (size_t)(e * F2 + n0 + brow) * F1;
    const int dA = tid * 16;
    const int dB0 = tid * 16, dB1 = tid * 16 + 4096;
    const int bo0 = bchk * 8, bo1 = bchk * 8 + 16;

    float4v acc[2][4] = {};
    int offa[2], offb[4];
    #pragma unroll
    for (int i = 0; i < 2; ++i) offa[i] = (quad * 64 + r0w + i * 16 + lrow) * 16;
    #pragma unroll
    for (int j = 0; j < 4; ++j) offb[j] = (quad * 128 + c0w + j * 16 + lrow) * 16;

    for (int k0 = 0; k0 < F1; k0 += 32) {
        __syncthreads();
        glds16(pxh + k0, SMc + dA);                 // A hi
        glds16(pxl + k0, SMc + 4096 + dA);          // A lo
        glds16(pbh + k0 + bo0, SMc + 8192 + dB0);   // B hi chunks 0-1
        glds16(pbh + k0 + bo1, SMc + 8192 + dB1);   // B hi chunks 2-3
        glds16(pbl + k0 + bo0, SMc + 16384 + dB0);  // B lo
        glds16(pbl + k0 + bo1, SMc + 16384 + dB1);
        __syncthreads();
        short8 ah[2], al[2];
        #pragma unroll
        for (int i = 0; i < 2; ++i) {
            ah[i] = *(const short8*)(SMc + offa[i]);
            al[i] = *(const short8*)(SMc + 4096 + offa[i]);
        }
        #pragma unroll
        for (int j = 0; j < 4; ++j) {
            short8 bh = *(const short8*)(SMc + 8192 + offb[j]);
            short8 bl = *(const short8*)(SMc + 16384 + offb[j]);
            #pragma unroll
            for (int i = 0; i < 2; ++i) {
                acc[i][j] = mfma16(ah[i], bh, acc[i][j]);
                acc[i][j] = mfma16(ah[i], bl, acc[i][j]);
                acc[i][j] = mfma16(al[i], bh, acc[i][j]);
            }
        }
    }

    // epilogue: +b1, relu, split; hi then lo via LDS transpose [64][136]
    float bv[4];
    #pragma unroll
    for (int j = 0; j < 4; ++j) bv[j] = b1[e * F2 + n0 + c0w + j * 16 + lrow];
    short* T = (short*)SMc;
    #pragma unroll
    for (int plane = 0; plane < 2; ++plane) {
        __syncthreads();
        #pragma unroll
        for (int i = 0; i < 2; ++i)
            #pragma unroll
            for (int j = 0; j < 4; ++j)
                #pragma unroll
                for (int r = 0; r < 4; ++r) {
                    const int m = r0w + i * 16 + quad * 4 + r;
                    const int n = c0w + j * 16 + lrow;
                    float hv = fmaxf(acc[i][j][r] + bv[j], 0.f);
                    short hi = bf16_rn(hv);
                    T[m * 136 + n] = plane ? bf16_rn(hv - bf16_up(hi)) : hi;
                }
        __syncthreads();
        short* dst = (plane ? hlo : hhi) + (size_t)(p0 + (tid >> 2)) * F2 + n0 + (tid & 3) * 32;
        const short* src = T + (tid >> 2) * 136 + (tid & 3) * 32;
        #pragma unroll
        for (int u = 0; u < 4; ++u)
            *(short8*)(dst + u * 8) = *(const short8*)(src + u * 8);
    }
}

// ---------------- GEMM2: 32 rows x 64 classes, BK=64, chunk-major staging; softmax ----------------
__global__ __launch_bounds__(256)
void dael_gemm2(const int* __restrict__ order, const int* __restrict__ bexp,
                const short* __restrict__ hhi, const short* __restrict__ hlo,
                const short* __restrict__ w2hi, const short* __restrict__ w2lo,
                const float* __restrict__ b2, float* __restrict__ out) {
    const int e = bexp[blockIdx.x >> 1];   // SEG=64, 32-row blocks
    if (e < 0) return;
    const int p0 = blockIdx.x * 32;
    const int tid = threadIdx.x;
    const int lane = tid & 63, wv = tid >> 6;
    const int quad = lane >> 4, lrow = lane & 15;

    __shared__ __align__(16) char SM2[24576]; // Ahi[8][32][16] Alo | Bhi[8][64][16] Blo
    __shared__ float L[32][68];
    __shared__ float inv[32];

    const int arow = tid & 31;
    const int acel = (tid >> 5) * 8;
    const int brow = tid & 63;
    const int bcel = (tid >> 6) * 8;
    const size_t abase = (size_t)(p0 + arow) * F2 + acel;
    const size_t bbase = (size_t)(e * NCLS + brow) * F2 + bcel;
    const int da = tid * 16;
    const int db1 = da + 4096;

    float4v acc[2] = {};

    for (int k0 = 0; k0 < F2; k0 += 64) {
        __syncthreads();
        glds16(hhi + abase + k0,       SM2 + da);             // A hi
        glds16(hlo + abase + k0,       SM2 + 4096 + da);      // A lo
        glds16(w2hi + bbase + k0,      SM2 + 8192 + da);      // B hi c0-3
        glds16(w2hi + bbase + k0 + 32, SM2 + 8192 + db1);     // B hi c4-7
        glds16(w2lo + bbase + k0,      SM2 + 16384 + da);     // B lo
        glds16(w2lo + bbase + k0 + 32, SM2 + 16384 + db1);
        __syncthreads();
        #pragma unroll
        for (int s = 0; s < 2; ++s) {
            const int ch = s * 4 + quad;
            const int bo = (ch * 64 + wv * 16 + lrow) * 16;
            short8 bh = *(const short8*)(SM2 + 8192 + bo);
            short8 bl = *(const short8*)(SM2 + 16384 + bo);
            #pragma unroll
            for (int i = 0; i < 2; ++i) {
                const int ao = (ch * 32 + i * 16 + lrow) * 16;
                short8 ahf = *(const short8*)(SM2 + ao);
                short8 alf = *(const short8*)(SM2 + 4096 + ao);
                acc[i] = mfma16(ahf, bh, acc[i]);
                acc[i] = mfma16(ahf, bl, acc[i]);
                acc[i] = mfma16(alf, bh, acc[i]);
            }
        }
    }

    const int n = wv * 16 + lrow;
    const float bb = b2[e * NCLS + n];
    #pragma unroll
    for (int i = 0; i < 2; ++i)
        #pragma unroll
        for (int r = 0; r < 4; ++r)
            L[i * 16 + quad * 4 + r][n] = acc[i][r] + bb;
    __syncthreads();
    if (tid < 32) {
        float mx = -3.402823466e38f;
        #pragma unroll 8
        for (int c = 0; c < NCLS; ++c) mx = fmaxf(mx, L[tid][c]);
        float s = 0.f;
        #pragma unroll 8
        for (int c = 0; c < NCLS; ++c) { float ev = __expf(L[tid][c] - mx); L[tid][c] = ev; s += ev; }
        inv[tid] = 1.f / s;
    }
    __syncthreads();
    if (tid < 128) {
        const int r = tid >> 2, cs = (tid & 3) * 16;
        const int samp = order[p0 + r];
        if (samp >= 0) {
            const float sc = inv[r];
            #pragma unroll
            for (int q = 0; q < 4; ++q) {
                float4 v = *(const float4*)&L[r][cs + q * 4];
                v.x *= sc; v.y *= sc; v.z *= sc; v.w *= sc;
                *(float4*)(out + (size_t)samp * NCLS + cs + q * 4) = v;
            }
        }
    }
}

extern "C" void kernel_launch(void* const* d_in, const int* in_sizes, int n_in,
                              void* d_out, int out_size, void* d_ws, size_t ws_size,
                              hipStream_t stream) {
    const int*   domain = (const int*)d_in[0];
    const float* x      = (const float*)d_in[1];
    const float* W1     = (const float*)d_in[2];
    const float* b1     = (const float*)d_in[3];
    const float* W2     = (const float*)d_in[4];
    const float* b2     = (const float*)d_in[5];
    float* out = (float*)d_out;

    char* ws = (char*)d_ws;
    int*   meta  = (int*)(ws + O_META);
    int*   bexp  = (int*)(ws + O_BEXP);
    int*   order = (int*)(ws + O_ORDER);
    short* zrow  = (short*)(ws + O_ZROW);
    short* xhi   = (short*)(ws + O_XHI);
    short* xlo   = (short*)(ws + O_XLO);
    short* w1hi  = (short*)(ws + O_W1HI);
    short* w1lo  = (short*)(ws + O_W1LO);
    short* w2hi  = (short*)(ws + O_W2HI);
    short* w2lo  = (short*)(ws + O_W2LO);
    short* hhi   = (short*)(ws + O_HHI);
    short* hlo   = (short*)(ws + O_HLO);

    dael_setup<<<1, 1024, 0, stream>>>(domain, meta, bexp, order, (int*)zrow);
    dael_scatter<<<BATCH / 256, 256, 0, stream>>>(domain, meta, order);
    dael_convert<<<NBX + NBW1 + NBW2, 256, 0, stream>>>(x, xhi, xlo, W1, w1hi, w1lo,
                                                        W2, w2hi, w2lo);
    dael_gemm1<<<dim3(NB1, 4), 256, 0, stream>>>(order, bexp, xhi, xlo, zrow,
                                                 w1hi, w1lo, b1, hhi, hlo);
    dael_gemm2<<<NB2, 256, 0, stream>>>(order, bexp, hhi, hlo, w2hi, w2lo, b2, out);
}

// Round 5
// 245.654 us; speedup vs baseline: 1.4766x; 1.2601x over previous
//
#include <hip/hip_runtime.h>
#include <hip/hip_bf16.h>

// Problem constants
#define BATCH 16384
#define F1    1024
#define F2    512
#define NCLS  64
#define NEXP  8
#define BPAD  (BATCH + NEXP*128)  // 17408 (segments padded to 128)
#define NBM   136                 // BPAD/128 gemm1 m-blocks
#define NBG1  544                 // NBM * 4 strips
#define NBG2  272                 // BPAD/64 gemm2 m-blocks

typedef __attribute__((ext_vector_type(8))) short short8;   // 8 bf16
typedef __attribute__((ext_vector_type(4))) float float4v;  // MFMA C/D

// Workspace layout (bytes); ~119.1 MB
#define O_META   0                       // [8..16) cursors, [16..24) bases, [64..576) partial hist
#define O_BEXP   4096                    // int[136]
#define O_ORDER  8192                    // int[17408]
#define O_XPH    131072                  // packed x hi tiles: [136 mb][32 ks][4 q][128 r][8]
#define O_XPL    (O_XPH + 35651584)
#define O_W1H    (O_XPL + 35651584)      // [8 e][4 strip][32 ks][4 q][128 n][8]
#define O_W1L    (O_W1H + 8388608)
#define O_W2H    (O_W1L + 8388608)       // [8 e][8 ks][8 q][64 c][8]
#define O_W2L    (O_W2H + 524288)
#define O_HH     (O_W2L + 524288)        // packed h hi tiles: [272 mb2][8 ks][8 q][64 r][8]
#define O_HL     (O_HH + 17825792)

__device__ inline short bf16_rn(float f) {
    unsigned u = __builtin_bit_cast(unsigned, f);
    u = (u + 0x7fffu + ((u >> 16) & 1u)) >> 16;
    return (short)u;
}
__device__ inline float bf16_up(short h) {
    return __builtin_bit_cast(float, ((unsigned)(unsigned short)h) << 16);
}
__device__ inline void split2(float v, short& hi, short& lo) {
    hi = bf16_rn(v);
    lo = bf16_rn(v - bf16_up(hi));
}
__device__ inline float4v mfma16(short8 a, short8 b, float4v c) {
    return __builtin_amdgcn_mfma_f32_16x16x32_bf16(a, b, c, 0, 0, 0);
}
__device__ inline void glds16(const void* g, void* l) {
    __builtin_amdgcn_global_load_lds((const __attribute__((address_space(1))) void*)g,
                                     (__attribute__((address_space(3))) void*)l,
                                     16, 0, 0);
}

// ---------------- init: order=-1 + per-block histogram (no atomics to global) ----------------
__global__ void dael_init(const int* __restrict__ domain, int* meta, int* order) {
    __shared__ int hc[NEXP];
    const int b = blockIdx.x, t = threadIdx.x;
    const int i = b * 256 + t;
    if (i < BPAD) order[i] = -1;
    if (b < 64) {
        if (t < NEXP) hc[t] = 0;
        __syncthreads();
        atomicAdd(&hc[domain[i]], 1);
        __syncthreads();
        if (t < NEXP) meta[64 + b * NEXP + t] = hc[t];
    }
}

// ---------------- plan: sum partials, bases/cursors, bexp (1 block) ----------------
__global__ void dael_plan(int* meta, int* bexp) {
    __shared__ int cnt[NEXP], soff[NEXP + 1];
    const int t = threadIdx.x;
    if (t < NEXP) {
        int s = 0;
        for (int b = 0; b < 64; ++b) s += meta[64 + b * NEXP + t];
        cnt[t] = s;
    }
    __syncthreads();
    if (t == 0) {
        int acc = 0;
        for (int e = 0; e < NEXP; ++e) {
            soff[e] = acc;
            meta[16 + e] = acc * 128;  // padded row base
            meta[8 + e] = 0;           // cursor
            acc += (cnt[e] + 127) >> 7;
        }
        soff[NEXP] = acc;
    }
    __syncthreads();
    for (int i = t; i < NBM; i += 256) {
        int ee = -1;
        #pragma unroll
        for (int e = 0; e < NEXP; ++e)
            if (i >= soff[e] && i < soff[e + 1]) ee = e;
        bexp[i] = ee;
    }
}

// ---------------- scatter: per-block LDS ranks ----------------
__global__ void dael_scatter(const int* __restrict__ domain, int* meta, int* order) {
    __shared__ int lc[NEXP], lb[NEXP];
    const int t = threadIdx.x;
    const int i = blockIdx.x * 256 + t;
    if (t < NEXP) lc[t] = 0;
    __syncthreads();
    const int d = domain[i];
    const int r = atomicAdd(&lc[d], 1);
    __syncthreads();
    if (t < NEXP && lc[t] > 0) lb[t] = atomicAdd(&meta[8 + t], lc[t]);
    __syncthreads();
    order[meta[16 + d] + lb[d] + r] = i;
}

// ---------------- pack mega-kernel: x (via order) | W1 | W2 -> chunk-major 8KB tiles ----------------
#define NPX 1088   // 136 mb x 8 kg
#define NPW1 1024  // 8 e x 4 strip x 32 ks
#define NPW2 64    // 8 e x 8 ks
__global__ __launch_bounds__(256)
void dael_pack(const int* __restrict__ order,
               const float* __restrict__ x, short* xph, short* xpl,
               const float* __restrict__ W1, short* w1h, short* w1l,
               const float* __restrict__ W2, short* w2h, short* w2l) {
    const int b = blockIdx.x, t = threadIdx.x;
    if (b < NPX) {
        const int mb = b >> 3, kg = b & 7;
        const int r = t & 127;                 // row (same for both slots)
        const int samp = order[mb * 128 + r];
        #pragma unroll
        for (int kl = 0; kl < 4; ++kl) {
            const int ks = kg * 4 + kl;
            const size_t tb = (size_t)(mb * 32 + ks) * 4096;
            #pragma unroll
            for (int sl = 0; sl < 2; ++sl) {
                const int s = t + sl * 256;
                const int q = s >> 7;
                short8 vh = {}, vl = {};
                if (samp >= 0) {
                    const float* src = x + (size_t)samp * F1 + ks * 32 + q * 8;
                    float4 f0 = *(const float4*)src;
                    float4 f1 = *(const float4*)(src + 4);
                    float va[8] = {f0.x, f0.y, f0.z, f0.w, f1.x, f1.y, f1.z, f1.w};
                    #pragma unroll
                    for (int i = 0; i < 8; ++i) { short h, l; split2(va[i], h, l); vh[i] = h; vl[i] = l; }
                }
                *(short8*)(xph + tb + s * 8) = vh;
                *(short8*)(xpl + tb + s * 8) = vl;
            }
        }
    } else if (b < NPX + NPW1) {
        const int b2 = b - NPX;
        const int e = b2 >> 7, strip = (b2 >> 5) & 3, ks = b2 & 31;
        const size_t tb = (size_t)((e * 4 + strip) * 32 + ks) * 4096;
        #pragma unroll
        for (int sl = 0; sl < 2; ++sl) {
            const int s = t + sl * 256;
            const int q = s >> 7, r = s & 127;
            const int n = strip * 128 + r;
            short8 vh, vl;
            #pragma unroll
            for (int jj = 0; jj < 8; ++jj) {
                const int k = ks * 32 + q * 8 + jj;
                float v = W1[((size_t)(e * F1 + k)) * F2 + n];
                short h, l; split2(v, h, l); vh[jj] = h; vl[jj] = l;
            }
            *(short8*)(w1h + tb + s * 8) = vh;
            *(short8*)(w1l + tb + s * 8) = vl;
        }
    } else {
        const int b3 = b - NPX - NPW1;
        const int e = b3 >> 3, ks = b3 & 7;
        const size_t tb = (size_t)(e * 8 + ks) * 4096;
        #pragma unroll
        for (int sl = 0; sl < 2; ++sl) {
            const int s = t + sl * 256;
            const int q = s >> 6, c = s & 63;
            short8 vh, vl;
            #pragma unroll
            for (int jj = 0; jj < 8; ++jj) {
                const int k = ks * 64 + q * 8 + jj;
                float v = W2[((size_t)(e * F2 + k)) * NCLS + c];
                short h, l; split2(v, h, l); vh[jj] = h; vl[jj] = l;
            }
            *(short8*)(w2h + tb + s * 8) = vh;
            *(short8*)(w2l + tb + s * 8) = vl;
        }
    }
}

// ---------------- GEMM1: 128x128, BK=32, 256 thr, packed-tile streaming ----------------
// blockIdx L: xcd=L&7, j=L>>3 -> mb = xcd*17 + j%17, strip = j/17 (L2 locality per XCD).
__global__ __launch_bounds__(256)
void dael_gemm1(const int* __restrict__ bexp,
                const short* __restrict__ xph, const short* __restrict__ xpl,
                const short* __restrict__ w1h, const short* __restrict__ w1l,
                const float* __restrict__ b1,
                short* __restrict__ hh, short* __restrict__ hl) {
    const int L = blockIdx.x;
    const int xcd = L & 7, j = L >> 3;
    const int mb = xcd * 17 + (j % 17);
    const int strip = j / 17;
    const int e = bexp[mb];
    if (e < 0) return;
    const int tid = threadIdx.x;
    const int lane = tid & 63, wv = tid >> 6;
    const int quad = lane >> 4, lrow = lane & 15;
    const int r0w = (wv & 1) * 64, c0w = (wv >> 1) * 64;

    __shared__ __align__(16) char SMc[34816];  // tiles 32 KB; epilogue T[128][136] = 34816 B

    const short* Ah = xph + (size_t)(mb * 32) * 4096 + tid * 8;
    const short* Al = xpl + (size_t)(mb * 32) * 4096 + tid * 8;
    const short* Bh = w1h + (size_t)((e * 4 + strip) * 32) * 4096 + tid * 8;
    const short* Bl = w1l + (size_t)((e * 4 + strip) * 32) * 4096 + tid * 8;
    const int d0 = tid * 16;

    float4v acc[4][4] = {};
    int offa[4], offb[4];
    #pragma unroll
    for (int i = 0; i < 4; ++i) offa[i] = quad * 2048 + (r0w + i * 16 + lrow) * 16;
    #pragma unroll
    for (int jj = 0; jj < 4; ++jj) offb[jj] = 16384 + quad * 2048 + (c0w + jj * 16 + lrow) * 16;

    for (int ks = 0; ks < 32; ++ks) {
        const int so = ks * 4096;
        __syncthreads();
        glds16(Ah + so,        SMc + d0);
        glds16(Ah + so + 2048, SMc + 4096 + d0);
        glds16(Al + so,        SMc + 8192 + d0);
        glds16(Al + so + 2048, SMc + 12288 + d0);
        glds16(Bh + so,        SMc + 16384 + d0);
        glds16(Bh + so + 2048, SMc + 20480 + d0);
        glds16(Bl + so,        SMc + 24576 + d0);
        glds16(Bl + so + 2048, SMc + 28672 + d0);
        __syncthreads();
        short8 ah[4], al[4];
        #pragma unroll
        for (int i = 0; i < 4; ++i) {
            ah[i] = *(const short8*)(SMc + offa[i]);
            al[i] = *(const short8*)(SMc + 8192 + offa[i]);
        }
        #pragma unroll
        for (int jj = 0; jj < 4; ++jj) {
            short8 bh = *(const short8*)(SMc + offb[jj]);
            short8 bl = *(const short8*)(SMc + 8192 + offb[jj]);
            #pragma unroll
            for (int i = 0; i < 4; ++i) {
                acc[i][jj] = mfma16(ah[i], bh, acc[i][jj]);
                acc[i][jj] = mfma16(ah[i], bl, acc[i][jj]);
                acc[i][jj] = mfma16(al[i], bh, acc[i][jj]);
            }
        }
    }

    // epilogue: +b1, relu, split; through LDS T[128][136]; store packed h tiles
    float bv[4];
    #pragma unroll
    for (int jj = 0; jj < 4; ++jj)
        bv[jj] = b1[e * F2 + strip * 128 + c0w + jj * 16 + lrow];
    short* T = (short*)SMc;
    #pragma unroll
    for (int plane = 0; plane < 2; ++plane) {
        __syncthreads();
        #pragma unroll
        for (int i = 0; i < 4; ++i)
            #pragma unroll
            for (int jj = 0; jj < 4; ++jj)
                #pragma unroll
                for (int r = 0; r < 4; ++r) {
                    const int m = r0w + i * 16 + quad * 4 + r;
                    const int n = c0w + jj * 16 + lrow;
                    float hv = fmaxf(acc[i][jj][r] + bv[jj], 0.f);
                    short hi = bf16_rn(hv);
                    T[m * 136 + n] = plane ? bf16_rn(hv - bf16_up(hi)) : hi;
                }
        __syncthreads();
        short* dst = plane ? hl : hh;
        #pragma unroll
        for (int u = 0; u < 8; ++u) {
            const int sidx = tid + 256 * u;          // 0..2047
            const int g = sidx >> 6, m64 = sidx & 63;
            const int mloc = g >> 4, ksl = (g >> 3) & 1, q = g & 7;
            const int m = mloc * 64 + m64;
            const int n = ksl * 64 + q * 8;
            const size_t off = ((size_t)((mb * 2 + mloc) * 8 + strip * 2 + ksl)) * 4096
                               + q * 512 + m64 * 8;
            *(short8*)(dst + off) = *(const short8*)&T[m * 136 + n];
        }
    }
}

// ---------------- GEMM2: 64 rows x 64 classes, BK=64, packed streaming; softmax ----------------
__global__ __launch_bounds__(256)
void dael_gemm2(const int* __restrict__ order, const int* __restrict__ bexp,
                const short* __restrict__ hh, const short* __restrict__ hl,
                const short* __restrict__ w2h, const short* __restrict__ w2l,
                const float* __restrict__ b2, float* __restrict__ out) {
    const int b = blockIdx.x;
    const int e = bexp[b >> 1];
    if (e < 0) return;
    const int p0 = b * 64;
    const int tid = threadIdx.x;
    const int lane = tid & 63, wv = tid >> 6;
    const int quad = lane >> 4, lrow = lane & 15;

    __shared__ __align__(16) char SM2[32768];
    __shared__ float inv[64];

    const short* Ah = hh + (size_t)(b * 8) * 4096 + tid * 8;
    const short* Al = hl + (size_t)(b * 8) * 4096 + tid * 8;
    const short* Bh = w2h + (size_t)(e * 8) * 4096 + tid * 8;
    const short* Bl = w2l + (size_t)(e * 8) * 4096 + tid * 8;
    const int d0 = tid * 16;

    float4v acc[4] = {};

    for (int ks = 0; ks < 8; ++ks) {
        const int so = ks * 4096;
        __syncthreads();
        glds16(Ah + so,        SM2 + d0);
        glds16(Ah + so + 2048, SM2 + 4096 + d0);
        glds16(Al + so,        SM2 + 8192 + d0);
        glds16(Al + so + 2048, SM2 + 12288 + d0);
        glds16(Bh + so,        SM2 + 16384 + d0);
        glds16(Bh + so + 2048, SM2 + 20480 + d0);
        glds16(Bl + so,        SM2 + 24576 + d0);
        glds16(Bl + so + 2048, SM2 + 28672 + d0);
        __syncthreads();
        #pragma unroll
        for (int ksub = 0; ksub < 2; ++ksub) {
            const int qa = (ksub * 4 + quad) * 1024;
            const int ao = qa + (wv * 16 + lrow) * 16;
            short8 ahf = *(const short8*)(SM2 + ao);
            short8 alf = *(const short8*)(SM2 + 8192 + ao);
            #pragma unroll
            for (int jj = 0; jj < 4; ++jj) {
                const int bo = 16384 + qa + (jj * 16 + lrow) * 16;
                short8 bh = *(const short8*)(SM2 + bo);
                short8 bl = *(const short8*)(SM2 + 8192 + bo);
                acc[jj] = mfma16(ahf, bh, acc[jj]);
                acc[jj] = mfma16(ahf, bl, acc[jj]);
                acc[jj] = mfma16(alf, bh, acc[jj]);
            }
        }
    }

    __syncthreads();
    float* Lx = (float*)SM2;               // [64][68]
    #pragma unroll
    for (int jj = 0; jj < 4; ++jj) {
        const int n = jj * 16 + lrow;
        const float bb = b2[e * NCLS + n];
        #pragma unroll
        for (int r = 0; r < 4; ++r)
            Lx[(wv * 16 + quad * 4 + r) * 68 + n] = acc[jj][r] + bb;
    }
    __syncthreads();
    if (tid < 64) {
        float mx = -3.402823466e38f;
        #pragma unroll 8
        for (int c = 0; c < NCLS; ++c) mx = fmaxf(mx, Lx[tid * 68 + c]);
        float s = 0.f;
        #pragma unroll 8
        for (int c = 0; c < NCLS; ++c) {
            float ev = __expf(Lx[tid * 68 + c] - mx);
            Lx[tid * 68 + c] = ev; s += ev;
        }
        inv[tid] = 1.f / s;
    }
    __syncthreads();
    const int r = tid >> 2, cs = (tid & 3) * 16;
    const int samp = order[p0 + r];
    if (samp >= 0) {
        const float sc = inv[r];
        #pragma unroll
        for (int q = 0; q < 4; ++q) {
            float4 v = *(const float4*)&Lx[r * 68 + cs + q * 4];
            v.x *= sc; v.y *= sc; v.z *= sc; v.w *= sc;
            *(float4*)(out + (size_t)samp * NCLS + cs + q * 4) = v;
        }
    }
}

extern "C" void kernel_launch(void* const* d_in, const int* in_sizes, int n_in,
                              void* d_out, int out_size, void* d_ws, size_t ws_size,
                              hipStream_t stream) {
    const int*   domain = (const int*)d_in[0];
    const float* x      = (const float*)d_in[1];
    const float* W1     = (const float*)d_in[2];
    const float* b1     = (const float*)d_in[3];
    const float* W2     = (const float*)d_in[4];
    const float* b2     = (const float*)d_in[5];
    float* out = (float*)d_out;

    char* ws = (char*)d_ws;
    int*   meta  = (int*)(ws + O_META);
    int*   bexp  = (int*)(ws + O_BEXP);
    int*   order = (int*)(ws + O_ORDER);
    short* xph   = (short*)(ws + O_XPH);
    short* xpl   = (short*)(ws + O_XPL);
    short* w1h   = (short*)(ws + O_W1H);
    short* w1l   = (short*)(ws + O_W1L);
    short* w2h   = (short*)(ws + O_W2H);
    short* w2l   = (short*)(ws + O_W2L);
    short* hh    = (short*)(ws + O_HH);
    short* hl    = (short*)(ws + O_HL);

    dael_init<<<68, 256, 0, stream>>>(domain, meta, order);
    dael_plan<<<1, 256, 0, stream>>>(meta, bexp);
    dael_scatter<<<64, 256, 0, stream>>>(domain, meta, order);
    dael_pack<<<NPX + NPW1 + NPW2, 256, 0, stream>>>(order, x, xph, xpl,
                                                     W1, w1h, w1l, W2, w2h, w2l);
    dael_gemm1<<<NBG1, 256, 0, stream>>>(bexp, xph, xpl, w1h, w1l, b1, hh, hl);
    dael_gemm2<<<NBG2, 256, 0, stream>>>(order, bexp, hh, hl, w2h, w2l, b2, out);
}

// Round 6
// 237.107 us; speedup vs baseline: 1.5299x; 1.0360x over previous
//
#include <hip/hip_runtime.h>
#include <hip/hip_bf16.h>

// Problem constants
#define BATCH 16384
#define F1    1024
#define F2    512
#define NCLS  64
#define NEXP  8
#define BPAD  (BATCH + NEXP*128)  // 17408 (segments padded to 128)
#define NBM   136                 // BPAD/128 gemm1 m-blocks
#define NBG1  544                 // NBM * 4 strips
#define NBG2  272                 // BPAD/64 gemm2 m-blocks

typedef __attribute__((ext_vector_type(8))) short short8;   // 8 bf16
typedef __attribute__((ext_vector_type(4))) float float4v;  // MFMA C/D

// Workspace layout (bytes); ~119.1 MB
#define O_META   0                       // [8..16) cursors, [16..24) bases, [64..576) partial hist
#define O_BEXP   4096                    // int[136]
#define O_ORDER  8192                    // int[17408]
#define O_XPH    131072                  // packed x hi tiles: [136 mb][32 ks][4 q][128 r][8]
#define O_XPL    (O_XPH + 35651584)
#define O_W1H    (O_XPL + 35651584)      // [8 e][4 strip][32 ks][4 q][128 n][8]
#define O_W1L    (O_W1H + 8388608)
#define O_W2H    (O_W1L + 8388608)       // [8 e][8 ks][8 q][64 c][8]
#define O_W2L    (O_W2H + 524288)
#define O_HH     (O_W2L + 524288)        // packed h hi tiles: [272 mb2][8 ks][8 q][64 r][8]
#define O_HL     (O_HH + 17825792)

__device__ inline short bf16_rn(float f) {
    unsigned u = __builtin_bit_cast(unsigned, f);
    u = (u + 0x7fffu + ((u >> 16) & 1u)) >> 16;
    return (short)u;
}
__device__ inline float bf16_up(short h) {
    return __builtin_bit_cast(float, ((unsigned)(unsigned short)h) << 16);
}
__device__ inline void split2(float v, short& hi, short& lo) {
    hi = bf16_rn(v);
    lo = bf16_rn(v - bf16_up(hi));
}
__device__ inline float4v mfma16(short8 a, short8 b, float4v c) {
    return __builtin_amdgcn_mfma_f32_16x16x32_bf16(a, b, c, 0, 0, 0);
}
__device__ inline void glds16(const void* g, void* l) {
    __builtin_amdgcn_global_load_lds((const __attribute__((address_space(1))) void*)g,
                                     (__attribute__((address_space(3))) void*)l,
                                     16, 0, 0);
}

// ---------------- init: order=-1 + per-block histogram ----------------
__global__ void dael_init(const int* __restrict__ domain, int* meta, int* order) {
    __shared__ int hc[NEXP];
    const int b = blockIdx.x, t = threadIdx.x;
    const int i = b * 256 + t;
    if (i < BPAD) order[i] = -1;
    if (b < 64) {
        if (t < NEXP) hc[t] = 0;
        __syncthreads();
        atomicAdd(&hc[domain[i]], 1);
        __syncthreads();
        if (t < NEXP) meta[64 + b * NEXP + t] = hc[t];
    }
}

// ---------------- plan: sum partials, bases/cursors, bexp (1 block) ----------------
__global__ void dael_plan(int* meta, int* bexp) {
    __shared__ int cnt[NEXP], soff[NEXP + 1];
    const int t = threadIdx.x;
    if (t < NEXP) {
        int s = 0;
        for (int b = 0; b < 64; ++b) s += meta[64 + b * NEXP + t];
        cnt[t] = s;
    }
    __syncthreads();
    if (t == 0) {
        int acc = 0;
        for (int e = 0; e < NEXP; ++e) {
            soff[e] = acc;
            meta[16 + e] = acc * 128;  // padded row base
            meta[8 + e] = 0;           // cursor
            acc += (cnt[e] + 127) >> 7;
        }
        soff[NEXP] = acc;
    }
    __syncthreads();
    for (int i = t; i < NBM; i += 256) {
        int ee = -1;
        #pragma unroll
        for (int e = 0; e < NEXP; ++e)
            if (i >= soff[e] && i < soff[e + 1]) ee = e;
        bexp[i] = ee;
    }
}

// ---------------- scatter: per-block LDS ranks ----------------
__global__ void dael_scatter(const int* __restrict__ domain, int* meta, int* order) {
    __shared__ int lc[NEXP], lb[NEXP];
    const int t = threadIdx.x;
    const int i = blockIdx.x * 256 + t;
    if (t < NEXP) lc[t] = 0;
    __syncthreads();
    const int d = domain[i];
    const int r = atomicAdd(&lc[d], 1);
    __syncthreads();
    if (t < NEXP && lc[t] > 0) lb[t] = atomicAdd(&meta[8 + t], lc[t]);
    __syncthreads();
    order[meta[16 + d] + lb[d] + r] = i;
}

// ---------------- pack mega-kernel: x (via order) | W1 | W2 -> chunk-major 8KB tiles ----------------
#define NPX 1088   // 136 mb x 8 kg
#define NPW1 1024  // 8 e x 4 strip x 32 ks
#define NPW2 64    // 8 e x 8 ks
__global__ __launch_bounds__(256)
void dael_pack(const int* __restrict__ order,
               const float* __restrict__ x, short* xph, short* xpl,
               const float* __restrict__ W1, short* w1h, short* w1l,
               const float* __restrict__ W2, short* w2h, short* w2l) {
    const int b = blockIdx.x, t = threadIdx.x;
    if (b < NPX) {
        const int mb = b >> 3, kg = b & 7;
        const int r = t & 127;                 // row (same for both slots)
        const int samp = order[mb * 128 + r];
        #pragma unroll
        for (int kl = 0; kl < 4; ++kl) {
            const int ks = kg * 4 + kl;
            const size_t tb = (size_t)(mb * 32 + ks) * 4096;
            #pragma unroll
            for (int sl = 0; sl < 2; ++sl) {
                const int s = t + sl * 256;
                const int q = s >> 7;
                short8 vh = {}, vl = {};
                if (samp >= 0) {
                    const float* src = x + (size_t)samp * F1 + ks * 32 + q * 8;
                    float4 f0 = *(const float4*)src;
                    float4 f1 = *(const float4*)(src + 4);
                    float va[8] = {f0.x, f0.y, f0.z, f0.w, f1.x, f1.y, f1.z, f1.w};
                    #pragma unroll
                    for (int i = 0; i < 8; ++i) { short h, l; split2(va[i], h, l); vh[i] = h; vl[i] = l; }
                }
                *(short8*)(xph + tb + s * 8) = vh;
                *(short8*)(xpl + tb + s * 8) = vl;
            }
        }
    } else if (b < NPX + NPW1) {
        const int b2 = b - NPX;
        const int e = b2 >> 7, strip = (b2 >> 5) & 3, ks = b2 & 31;
        const size_t tb = (size_t)((e * 4 + strip) * 32 + ks) * 4096;
        #pragma unroll
        for (int sl = 0; sl < 2; ++sl) {
            const int s = t + sl * 256;
            const int q = s >> 7, r = s & 127;
            const int n = strip * 128 + r;
            short8 vh, vl;
            #pragma unroll
            for (int jj = 0; jj < 8; ++jj) {
                const int k = ks * 32 + q * 8 + jj;
                float v = W1[((size_t)(e * F1 + k)) * F2 + n];
                short h, l; split2(v, h, l); vh[jj] = h; vl[jj] = l;
            }
            *(short8*)(w1h + tb + s * 8) = vh;
            *(short8*)(w1l + tb + s * 8) = vl;
        }
    } else {
        const int b3 = b - NPX - NPW1;
        const int e = b3 >> 3, ks = b3 & 7;
        const size_t tb = (size_t)(e * 8 + ks) * 4096;
        #pragma unroll
        for (int sl = 0; sl < 2; ++sl) {
            const int s = t + sl * 256;
            const int q = s >> 6, c = s & 63;
            short8 vh, vl;
            #pragma unroll
            for (int jj = 0; jj < 8; ++jj) {
                const int k = ks * 64 + q * 8 + jj;
                float v = W2[((size_t)(e * F2 + k)) * NCLS + c];
                short h, l; split2(v, h, l); vh[jj] = h; vl[jj] = l;
            }
            *(short8*)(w2h + tb + s * 8) = vh;
            *(short8*)(w2l + tb + s * 8) = vl;
        }
    }
}

// ---------------- GEMM1: 128x128, BK=32, double-buffered LDS, 1 barrier/iter ----------------
__global__ __launch_bounds__(256)
void dael_gemm1(const int* __restrict__ bexp,
                const short* __restrict__ xph, const short* __restrict__ xpl,
                const short* __restrict__ w1h, const short* __restrict__ w1l,
                const float* __restrict__ b1,
                short* __restrict__ hh, short* __restrict__ hl) {
    const int L = blockIdx.x;
    const int xcd = L & 7, j = L >> 3;
    const int mb = xcd * 17 + (j % 17);
    const int strip = j / 17;
    const int e = bexp[mb];
    if (e < 0) return;
    const int tid = threadIdx.x;
    const int lane = tid & 63, wv = tid >> 6;
    const int quad = lane >> 4, lrow = lane & 15;
    const int r0w = (wv & 1) * 64, c0w = (wv >> 1) * 64;

    __shared__ __align__(16) char SMc[65536];  // 2 x 32KB double buffer; epilogue reuses

    const short* Ah = xph + (size_t)(mb * 32) * 4096 + tid * 8;
    const short* Al = xpl + (size_t)(mb * 32) * 4096 + tid * 8;
    const short* Bh = w1h + (size_t)((e * 4 + strip) * 32) * 4096 + tid * 8;
    const short* Bl = w1l + (size_t)((e * 4 + strip) * 32) * 4096 + tid * 8;
    const int d0 = tid * 16;

    float4v acc[4][4] = {};
    int offa[4], offb[4];
    #pragma unroll
    for (int i = 0; i < 4; ++i) offa[i] = quad * 2048 + (r0w + i * 16 + lrow) * 16;
    #pragma unroll
    for (int jj = 0; jj < 4; ++jj) offb[jj] = 16384 + quad * 2048 + (c0w + jj * 16 + lrow) * 16;

    // prologue: stage ks=0 into buf0
    {
        glds16(Ah,        SMc + d0);
        glds16(Ah + 2048, SMc + 4096 + d0);
        glds16(Al,        SMc + 8192 + d0);
        glds16(Al + 2048, SMc + 12288 + d0);
        glds16(Bh,        SMc + 16384 + d0);
        glds16(Bh + 2048, SMc + 20480 + d0);
        glds16(Bl,        SMc + 24576 + d0);
        glds16(Bl + 2048, SMc + 28672 + d0);
    }

    for (int ks = 0; ks < 32; ++ks) {
        __syncthreads();   // drains buf[ks&1] writes (vmcnt) + prior reads of buf[(ks+1)&1] (lgkmcnt)
        if (ks + 1 < 32) {
            const int so = (ks + 1) * 4096;
            const int db = ((ks + 1) & 1) * 32768;
            glds16(Ah + so,        SMc + db + d0);
            glds16(Ah + so + 2048, SMc + db + 4096 + d0);
            glds16(Al + so,        SMc + db + 8192 + d0);
            glds16(Al + so + 2048, SMc + db + 12288 + d0);
            glds16(Bh + so,        SMc + db + 16384 + d0);
            glds16(Bh + so + 2048, SMc + db + 20480 + d0);
            glds16(Bl + so,        SMc + db + 24576 + d0);
            glds16(Bl + so + 2048, SMc + db + 28672 + d0);
        }
        const int db = (ks & 1) * 32768;
        short8 ah[4], al[4];
        #pragma unroll
        for (int i = 0; i < 4; ++i) {
            ah[i] = *(const short8*)(SMc + db + offa[i]);
            al[i] = *(const short8*)(SMc + db + 8192 + offa[i]);
        }
        #pragma unroll
        for (int jj = 0; jj < 4; ++jj) {
            short8 bh = *(const short8*)(SMc + db + offb[jj]);
            short8 bl = *(const short8*)(SMc + db + 8192 + offb[jj]);
            #pragma unroll
            for (int i = 0; i < 4; ++i) {
                acc[i][jj] = mfma16(ah[i], bh, acc[i][jj]);
                acc[i][jj] = mfma16(ah[i], bl, acc[i][jj]);
                acc[i][jj] = mfma16(al[i], bh, acc[i][jj]);
            }
        }
    }

    // epilogue: +b1, relu, split; through LDS T[128][136]; store packed h tiles
    float bv[4];
    #pragma unroll
    for (int jj = 0; jj < 4; ++jj)
        bv[jj] = b1[e * F2 + strip * 128 + c0w + jj * 16 + lrow];
    short* T = (short*)SMc;
    #pragma unroll
    for (int plane = 0; plane < 2; ++plane) {
        __syncthreads();
        #pragma unroll
        for (int i = 0; i < 4; ++i)
            #pragma unroll
            for (int jj = 0; jj < 4; ++jj)
                #pragma unroll
                for (int r = 0; r < 4; ++r) {
                    const int m = r0w + i * 16 + quad * 4 + r;
                    const int n = c0w + jj * 16 + lrow;
                    float hv = fmaxf(acc[i][jj][r] + bv[jj], 0.f);
                    short hi = bf16_rn(hv);
                    T[m * 136 + n] = plane ? bf16_rn(hv - bf16_up(hi)) : hi;
                }
        __syncthreads();
        short* dst = plane ? hl : hh;
        #pragma unroll
        for (int u = 0; u < 8; ++u) {
            const int sidx = tid + 256 * u;          // 0..2047
            const int g = sidx >> 6, m64 = sidx & 63;
            const int mloc = g >> 4, ksl = (g >> 3) & 1, q = g & 7;
            const int m = mloc * 64 + m64;
            const int n = ksl * 64 + q * 8;
            const size_t off = ((size_t)((mb * 2 + mloc) * 8 + strip * 2 + ksl)) * 4096
                               + q * 512 + m64 * 8;
            *(short8*)(dst + off) = *(const short8*)&T[m * 136 + n];
        }
    }
}

// ---------------- GEMM2: 64x64, BK=64, double-buffered; softmax ----------------
__global__ __launch_bounds__(256)
void dael_gemm2(const int* __restrict__ order, const int* __restrict__ bexp,
                const short* __restrict__ hh, const short* __restrict__ hl,
                const short* __restrict__ w2h, const short* __restrict__ w2l,
                const float* __restrict__ b2, float* __restrict__ out) {
    const int b = blockIdx.x;
    const int e = bexp[b >> 1];
    if (e < 0) return;
    const int p0 = b * 64;
    const int tid = threadIdx.x;
    const int lane = tid & 63, wv = tid >> 6;
    const int quad = lane >> 4, lrow = lane & 15;

    __shared__ __align__(16) char SM2[65536];  // 2 x 32KB double buffer; softmax reuses
    __shared__ float inv[64];

    const short* Ah = hh + (size_t)(b * 8) * 4096 + tid * 8;
    const short* Al = hl + (size_t)(b * 8) * 4096 + tid * 8;
    const short* Bh = w2h + (size_t)(e * 8) * 4096 + tid * 8;
    const short* Bl = w2l + (size_t)(e * 8) * 4096 + tid * 8;
    const int d0 = tid * 16;

    float4v acc[4] = {};

    {
        glds16(Ah,        SM2 + d0);
        glds16(Ah + 2048, SM2 + 4096 + d0);
        glds16(Al,        SM2 + 8192 + d0);
        glds16(Al + 2048, SM2 + 12288 + d0);
        glds16(Bh,        SM2 + 16384 + d0);
        glds16(Bh + 2048, SM2 + 20480 + d0);
        glds16(Bl,        SM2 + 24576 + d0);
        glds16(Bl + 2048, SM2 + 28672 + d0);
    }

    for (int ks = 0; ks < 8; ++ks) {
        __syncthreads();
        if (ks + 1 < 8) {
            const int so = (ks + 1) * 4096;
            const int db = ((ks + 1) & 1) * 32768;
            glds16(Ah + so,        SM2 + db + d0);
            glds16(Ah + so + 2048, SM2 + db + 4096 + d0);
            glds16(Al + so,        SM2 + db + 8192 + d0);
            glds16(Al + so + 2048, SM2 + db + 12288 + d0);
            glds16(Bh + so,        SM2 + db + 16384 + d0);
            glds16(Bh + so + 2048, SM2 + db + 20480 + d0);
            glds16(Bl + so,        SM2 + db + 24576 + d0);
            glds16(Bl + so + 2048, SM2 + db + 28672 + d0);
        }
        const int db = (ks & 1) * 32768;
        #pragma unroll
        for (int ksub = 0; ksub < 2; ++ksub) {
            const int qa = (ksub * 4 + quad) * 1024;
            const int ao = db + qa + (wv * 16 + lrow) * 16;
            short8 ahf = *(const short8*)(SM2 + ao);
            short8 alf = *(const short8*)(SM2 + 8192 + ao);
            #pragma unroll
            for (int jj = 0; jj < 4; ++jj) {
                const int bo = db + 16384 + qa + (jj * 16 + lrow) * 16;
                short8 bh = *(const short8*)(SM2 + bo);
                short8 bl = *(const short8*)(SM2 + 8192 + bo);
                acc[jj] = mfma16(ahf, bh, acc[jj]);
                acc[jj] = mfma16(ahf, bl, acc[jj]);
                acc[jj] = mfma16(alf, bh, acc[jj]);
            }
        }
    }

    __syncthreads();
    float* Lx = (float*)SM2;               // [64][68]
    #pragma unroll
    for (int jj = 0; jj < 4; ++jj) {
        const int n = jj * 16 + lrow;
        const float bb = b2[e * NCLS + n];
        #pragma unroll
        for (int r = 0; r < 4; ++r)
            Lx[(wv * 16 + quad * 4 + r) * 68 + n] = acc[jj][r] + bb;
    }
    __syncthreads();
    if (tid < 64) {
        float mx = -3.402823466e38f;
        #pragma unroll 8
        for (int c = 0; c < NCLS; ++c) mx = fmaxf(mx, Lx[tid * 68 + c]);
        float s = 0.f;
        #pragma unroll 8
        for (int c = 0; c < NCLS; ++c) {
            float ev = __expf(Lx[tid * 68 + c] - mx);
            Lx[tid * 68 + c] = ev; s += ev;
        }
        inv[tid] = 1.f / s;
    }
    __syncthreads();
    const int r = tid >> 2, cs = (tid & 3) * 16;
    const int samp = order[p0 + r];
    if (samp >= 0) {
        const float sc = inv[r];
        #pragma unroll
        for (int q = 0; q < 4; ++q) {
            float4 v = *(const float4*)&Lx[r * 68 + cs + q * 4];
            v.x *= sc; v.y *= sc; v.z *= sc; v.w *= sc;
            *(float4*)(out + (size_t)samp * NCLS + cs + q * 4) = v;
        }
    }
}

extern "C" void kernel_launch(void* const* d_in, const int* in_sizes, int n_in,
                              void* d_out, int out_size, void* d_ws, size_t ws_size,
                              hipStream_t stream) {
    const int*   domain = (const int*)d_in[0];
    const float* x      = (const float*)d_in[1];
    const float* W1     = (const float*)d_in[2];
    const float* b1     = (const float*)d_in[3];
    const float* W2     = (const float*)d_in[4];
    const float* b2     = (const float*)d_in[5];
    float* out = (float*)d_out;

    char* ws = (char*)d_ws;
    int*   meta  = (int*)(ws + O_META);
    int*   bexp  = (int*)(ws + O_BEXP);
    int*   order = (int*)(ws + O_ORDER);
    short* xph   = (short*)(ws + O_XPH);
    short* xpl   = (short*)(ws + O_XPL);
    short* w1h   = (short*)(ws + O_W1H);
    short* w1l   = (short*)(ws + O_W1L);
    short* w2h   = (short*)(ws + O_W2H);
    short* w2l   = (short*)(ws + O_W2L);
    short* hh    = (short*)(ws + O_HH);
    short* hl    = (short*)(ws + O_HL);

    dael_init<<<68, 256, 0, stream>>>(domain, meta, order);
    dael_plan<<<1, 256, 0, stream>>>(meta, bexp);
    dael_scatter<<<64, 256, 0, stream>>>(domain, meta, order);
    dael_pack<<<NPX + NPW1 + NPW2, 256, 0, stream>>>(order, x, xph, xpl,
                                                     W1, w1h, w1l, W2, w2h, w2l);
    dael_gemm1<<<NBG1, 256, 0, stream>>>(bexp, xph, xpl, w1h, w1l, b1, hh, hl);
    dael_gemm2<<<NBG2, 256, 0, stream>>>(order, bexp, hh, hl, w2h, w2l, b2, out);
}